// Round 4
// baseline (165.762 us; speedup 1.0000x reference)
//
#include <hip/hip_runtime.h>
#include <cstdint>
#include <cstddef>

#define NB 128      // N
#define KPP 32      // Kp
#define VV 2048     // V
#define SS 200      // S (tm1)
#define WID 32      // width == K
#define NEXT_BASE (KPP*VV)     // 65536
#define SLICES 16
#define KROWS (KPP/SLICES)     // 2
#define SCAND (KROWS*VV)       // 4096 candidates per slice block
#define CAPA 512               // survivor capacity (slice)
#define NLIST (SLICES*WID + WID)   // 544 merge candidates

// output layout (flat f32, concat in return order)
#define SZ_YNEXT ((size_t)(SS+1)*NB*WID)               // 823296
#define NK       ((size_t)NB*WID)                      // 4096
#define O_LAST   (SZ_YNEXT)
#define O_LENS   (SZ_YNEXT + NK)
#define O_NB     (SZ_YNEXT + 2*NK)
#define O_B      (SZ_YNEXT + 3*NK)
#define O_PREF   (SZ_YNEXT + 4*NK)                     // size NB*WID*WID
#define O_SRC    (SZ_YNEXT + 4*NK + (size_t)NB*WID*WID)
#define O_NOEXT  (SZ_YNEXT + 5*NK + (size_t)NB*WID*WID)

__device__ __forceinline__ unsigned fkey(float f) {
    unsigned u = __float_as_uint(f);
    return (u & 0x80000000u) ? ~u : (u | 0x80000000u);
}
__device__ __forceinline__ float funkey(unsigned k) {
    unsigned u = (k & 0x80000000u) ? (k & 0x7FFFFFFFu) : ~k;
    return __uint_as_float(u);
}

// ---------------- kernel A: per-slice exact top-32 ----------------
__global__ __launch_bounds__(256) void slice_topk_kernel(
    const float* __restrict__ ext,     // [N][Kp][V]
    const float* __restrict__ nbp_g,   // [N][Kp]
    const float* __restrict__ bp_g,    // [N][Kp]
    const int*   __restrict__ yprev,   // [S][N][Kp]
    const int*   __restrict__ ylast,   // [N][Kp]
    const int*   __restrict__ ylens,   // [N][Kp]
    const int*   __restrict__ pip,     // [N][Kp][Kp]
    unsigned* __restrict__ wsF, int* __restrict__ wsI)
{
    const int blk  = blockIdx.x;
    const int n    = blk >> 4;
    const int s    = blk & 15;
    const int k0   = s * KROWS;
    const int tid  = threadIdx.x;
    const int lane = tid & 63, wv = tid >> 6;

    __shared__ float    s_ext[SCAND];          // 16 KB
    __shared__ unsigned s_hist[4096];          // 16 KB
    __shared__ unsigned s_coarse[256];
    __shared__ int      s_last[KROWS];
    __shared__ float    s_nbp[KROWS], s_bp[KROWS];
    __shared__ unsigned s_hm[KROWS][VV/32];    // 512 B
    __shared__ int      s_fb, s_gg, s_cnt;
    __shared__ unsigned s_lf[CAPA];
    __shared__ int      s_li[CAPA];
    __shared__ int      s_part[2][4];

    // stage ext slice (coalesced float4)
    const float4* g4 = (const float4*)(ext + ((size_t)n*KPP + k0)*VV);
    float4* l4 = (float4*)s_ext;
    #pragma unroll
    for (int i = 0; i < SCAND/4/256; ++i) l4[tid + i*256] = g4[tid + i*256];

    if (tid < KROWS*(VV/32)) ((unsigned*)s_hm)[tid] = 0u;
    if (tid == 0) s_cnt = 0;
    if (tid < KROWS) {
        int k = k0 + tid;
        int last = ylast[n*KPP + k]; last = min(max(last, 0), VV-1);
        s_last[tid] = last;
        s_nbp[tid]  = nbp_g[n*KPP + k];
        s_bp[tid]   = bp_g[n*KPP + k];
    }
    __syncthreads();
    if (tid < KROWS*KPP) {     // has_match bits for this slice's k rows
        int lk = tid >> 5, j = tid & 31;
        int k = k0 + lk;
        int tlen = ylens[n*KPP + k];
        int tcl  = min(max(tlen, 0), SS-1);
        int tm   = yprev[((size_t)tcl*NB + n)*KPP + j];
        tm = min(max(tm, 0), VV-1);
        bool ex = (tlen + 1 == ylens[n*KPP + j]) && (pip[((size_t)n*KPP + k)*KPP + j] != 0);
        if (ex) atomicOr(&s_hm[lk][tm >> 5], 1u << (tm & 31));
    }
    __syncthreads();

#define SKEY(q, kk) { \
        int lk_ = (q) >> 11, v_ = (q) & (VV-1); \
        float val_ = (((v_ == s_last[lk_]) ? 0.0f : s_nbp[lk_]) + s_bp[lk_]) * s_ext[q]; \
        if ((s_hm[lk_][v_ >> 5] >> (v_ & 31)) & 1u) val_ = -INFINITY; \
        kk = fkey(val_); }

    // histogram cascade: levels (shift 32->20->8->0), bins 4096/4096/256
    unsigned pref = 0;
    int shift = 32, need = WID, G = 0, c = 0;
    for (int lvl = 0; lvl < 3; ++lvl) {
        const int nsh   = (lvl == 0) ? 20 : (lvl == 1) ? 8 : 0;
        const int nbins = (lvl < 2) ? 4096 : 256;
        const unsigned bmask = (unsigned)(nbins - 1);
        for (int i = tid; i < nbins; i += 256) s_hist[i] = 0u;
        __syncthreads();
        for (int i = 0; i < SCAND/256; ++i) {
            int q = tid + (i << 8);
            unsigned kk; SKEY(q, kk);
            if (lvl == 0 || (kk >> shift) == pref)
                atomicAdd(&s_hist[(kk >> nsh) & bmask], 1u);
        }
        __syncthreads();
        const int chunk = nbins >> 8;          // 16 or 1
        unsigned cs = 0;
        for (int t = 0; t < chunk; ++t) cs += s_hist[tid*chunk + t];
        s_coarse[tid] = cs;
        __syncthreads();
        for (int off = 1; off < 256; off <<= 1) {   // inclusive suffix scan
            unsigned add = (tid + off < 256) ? s_coarse[tid + off] : 0u;
            __syncthreads();
            s_coarse[tid] += add;
            __syncthreads();
        }
        {   // unique crossing coarse bin -> fine bin
            int hi = (tid == 255) ? 0 : (int)s_coarse[tid + 1];
            if (hi < need && need <= (int)s_coarse[tid]) {
                int g = hi, fstar = tid*chunk;
                for (int f = tid*chunk + chunk - 1; f >= tid*chunk; --f) {
                    int h = (int)s_hist[f];
                    if (g < need && need <= g + h) { fstar = f; break; }
                    g += h;
                }
                s_fb = fstar; s_gg = g;
            }
        }
        __syncthreads();
        int fstar = s_fb, gl = s_gg;
        int bcnt  = (int)s_hist[fstar];
        pref  = (pref << (shift - nsh)) | (unsigned)fstar;
        shift = nsh;
        G += gl; need -= gl;
        c = G + bcnt;
        __syncthreads();     // protect s_hist reuse next level
        if (c <= CAPA) break;
    }

    if (c <= CAPA) {
        for (int i = 0; i < SCAND/256; ++i) {
            int q = tid + (i << 8);
            unsigned kk; SKEY(q, kk);
            if ((kk >> shift) >= pref) {
                int slot = atomicAdd(&s_cnt, 1);
                s_lf[slot] = kk; s_li[slot] = (k0 << 11) + q;
            }
        }
        __syncthreads();
    } else {
        // pathological: pref is exact key T; idx-radix over ties (LDS-resident)
        const unsigned T = pref;
        int pp = 0;
        unsigned istar = 0;
        for (int b = 11; b >= 0; --b) {
            int cnt = 0;
            for (int i = 0; i < SCAND/256; ++i) {
                int q = tid + (i << 8);
                unsigned kk; SKEY(q, kk);
                unsigned uq = (unsigned)q;
                if (kk == T && (uq >> (b+1)) == (istar >> (b+1)) && !((uq >> b) & 1u)) cnt++;
            }
            #pragma unroll
            for (int off = 32; off; off >>= 1) cnt += __shfl_xor(cnt, off);
            if (lane == 0) s_part[pp][wv] = cnt;
            __syncthreads();
            int tot = s_part[pp][0] + s_part[pp][1] + s_part[pp][2] + s_part[pp][3];
            pp ^= 1;
            if (tot >= need) { } else { need -= tot; istar |= (1u << b); }
        }
        for (int i = 0; i < SCAND/256; ++i) {
            int q = tid + (i << 8);
            unsigned kk; SKEY(q, kk);
            if (kk > T || (kk == T && (unsigned)q <= istar)) {
                int slot = atomicAdd(&s_cnt, 1);
                s_lf[slot] = kk; s_li[slot] = (k0 << 11) + q;
            }
        }
        __syncthreads();
    }
    const int cc = s_cnt;

    // rank-sort survivors, write slice top-32 sorted to ws
    for (int e = tid; e < cc; e += 256) {
        unsigned mf = s_lf[e]; int mi = s_li[e];
        int rank = 0;
        for (int j = 0; j < cc; ++j) {
            unsigned f = s_lf[j];
            rank += (f > mf || (f == mf && s_li[j] < mi)) ? 1 : 0;
        }
        if (rank < WID) { wsF[blk*WID + rank] = mf; wsI[blk*WID + rank] = mi; }
    }
#undef SKEY
}

// ---------------- kernel B: merge + epilogue + y_next + prefix ----------------
__global__ __launch_bounds__(256) void merge_kernel(
    const float* __restrict__ ext,
    const float* __restrict__ nonext,
    const float* __restrict__ blank,
    const float* __restrict__ nbp_g,
    const float* __restrict__ bp_g,
    const int*   __restrict__ yprev,
    const int*   __restrict__ ylast,
    const int*   __restrict__ ylens,
    const int*   __restrict__ pip,
    const unsigned* __restrict__ wsF, const int* __restrict__ wsI,
    float* __restrict__ out)
{
    const int n   = blockIdx.x;
    const int tid = threadIdx.x;

    __shared__ int      s_last[KPP];
    __shared__ float    s_nbp[KPP], s_bp[KPP], s_bne[KPP], s_nbne[KPP];
    __shared__ int      s_tm[KPP][KPP];
    __shared__ unsigned s_exact[KPP];
    __shared__ unsigned s_cf[NLIST];
    __shared__ int      s_ci[NLIST];
    __shared__ int      s_selidx[WID];
    __shared__ float    s_selval[WID];
    __shared__ int      s_r_src[WID], s_r_lens[WID], s_r_ext[WID], s_r_noext[WID];

    if (tid < KPP) {
        int k = tid;
        s_exact[k] = 0u;
        int last = ylast[n*KPP + k]; last = min(max(last, 0), VV-1);
        float a = nbp_g[n*KPP + k], b = bp_g[n*KPP + k];
        s_last[k] = last; s_nbp[k] = a; s_bp[k] = b;
        s_bne[k]  = (a + b) * blank[n];
        s_nbne[k] = a * nonext[(size_t)n*VV + last];
    }
    __syncthreads();
    for (int i = tid; i < KPP*KPP; i += 256) {   // (k,j) pairs
        int k = i >> 5, j = i & 31;
        int tlen = ylens[n*KPP + k];
        int tcl  = min(max(tlen, 0), SS-1);
        int tm   = yprev[((size_t)tcl*NB + n)*KPP + j];
        tm = min(max(tm, 0), VV-1);
        s_tm[k][j] = tm;
        bool ex = (tlen + 1 == ylens[n*KPP + j]) && (pip[((size_t)n*KPP + k)*KPP + j] != 0);
        if (ex) atomicOr(&s_exact[k], 1u << j);
    }
    __syncthreads();
    if (tid < KPP) {    // absorb (deterministic k-order)
        int j = tid;
        float acc = s_nbne[j];
        for (int k = 0; k < KPP; ++k) {
            if ((s_exact[k] >> j) & 1u) {
                int v = s_tm[k][j];
                float base = (v == s_last[k]) ? 0.0f : s_nbp[k];
                acc += (base + s_bp[k]) * ext[((size_t)n*KPP + k)*VV + v];
            }
        }
        s_nbne[j] = acc;
    }
    __syncthreads();

    // build merge list: 512 slice winners + 32 nonext
    for (int i = tid; i < NLIST; i += 256) {
        if (i < SLICES*WID) {
            s_cf[i] = wsF[n*SLICES*WID + i];
            s_ci[i] = wsI[n*SLICES*WID + i];
        } else {
            int j = i - SLICES*WID;
            s_cf[i] = fkey(s_nbne[j] + s_bne[j]);
            s_ci[i] = NEXT_BASE + j;
        }
    }
    __syncthreads();

    // exact rank among 544 (value desc, idx asc); rank<32 = output position
    for (int e = tid; e < NLIST; e += 256) {
        unsigned mf = s_cf[e]; int mi = s_ci[e];
        int rank = 0;
        for (int j = 0; j < NLIST; ++j) {
            unsigned f = s_cf[j];
            rank += (f > mf || (f == mf && s_ci[j] < mi)) ? 1 : 0;
        }
        if (rank < WID) { s_selidx[rank] = mi; s_selval[rank] = funkey(mf); }
    }
    __syncthreads();

    // epilogue: per-k scalar outputs
    if (tid < WID) {
        int k = tid;
        int ind = s_selidx[k];
        bool noext = ind >= NEXT_BASE;
        int src  = noext ? (ind - NEXT_BASE) : (ind >> 11);
        int extk = ind & (VV-1);
        int plen = ylens[n*KPP + src];
        int lens = plen + (noext ? 0 : 1);
        float nbv = noext ? s_nbne[src] : s_selval[k];
        float bv  = noext ? s_bne[src]  : 0.0f;
        int lastv = noext ? s_last[src] : extk;
        size_t o = (size_t)n*WID + k;
        out[O_LAST  + o] = (float)lastv;
        out[O_LENS  + o] = (float)lens;
        out[O_NB    + o] = nbv;
        out[O_B     + o] = bv;
        out[O_SRC   + o] = (float)src;
        out[O_NOEXT + o] = noext ? 1.0f : 0.0f;
        s_r_src[k] = src; s_r_lens[k] = lens; s_r_ext[k] = extk;
        s_r_noext[k] = noext ? 1 : 0;
    }
    __syncthreads();

    // fused next_is_prefix
    for (int i = tid; i < WID*WID; i += 256) {
        int k = i >> 5, j = i & 31;
        int src_j = s_r_src[j];
        int no_k  = s_r_noext[k], no_j = s_r_noext[j];
        int lens_k = s_r_lens[k], lens_j = s_r_lens[j];
        int plen_j = lens_j - (no_j ? 0 : 1);
        bool prefix = pip[((size_t)n*KPP + s_r_src[k])*KPP + src_j] != 0;
        bool leq    = lens_k <= lens_j;
        int  tstar  = max(lens_k - 1, 0);
        int  tmj;
        if (tstar == plen_j)   tmj = s_r_ext[j];
        else if (tstar < SS)   tmj = yprev[((size_t)tstar*NB + n)*KPP + src_j];
        else                   tmj = 0;
        bool res = prefix && leq && (no_k || (tmj == s_r_ext[k]));
        out[O_PREF + (size_t)n*WID*WID + i] = res ? 1.0f : 0.0f;
    }

    // fused y_next: out[t][n][k]
    for (int id = tid; id < (SS+1)*WID; id += 256) {
        int t = id >> 5, k = id & 31;
        int src  = s_r_src[k];
        int plen = s_r_lens[k] - (s_r_noext[k] ? 0 : 1);
        float val;
        if (t == plen)   val = (float)s_r_ext[k];
        else if (t < SS) val = (float)yprev[((size_t)t*NB + n)*KPP + src];
        else             val = 0.0f;
        out[(size_t)t*NK + (size_t)n*WID + k] = val;
    }
}

extern "C" void kernel_launch(void* const* d_in, const int* in_sizes, int n_in,
                              void* d_out, int out_size, void* d_ws, size_t ws_size,
                              hipStream_t stream) {
    const float* ext    = (const float*)d_in[0];
    const float* nonext = (const float*)d_in[1];
    const float* blank  = (const float*)d_in[2];
    const float* nbp    = (const float*)d_in[3];
    const float* bp     = (const float*)d_in[4];
    const int*   yprev  = (const int*)d_in[5];
    const int*   ylast  = (const int*)d_in[6];
    const int*   ylens  = (const int*)d_in[7];
    const int*   pip    = (const int*)d_in[8];
    float* out = (float*)d_out;

    unsigned* wsF = (unsigned*)d_ws;                     // 2048*32 u32
    int*      wsI = (int*)d_ws + NB*SLICES*WID;          // 2048*32 i32

    slice_topk_kernel<<<NB*SLICES, 256, 0, stream>>>(ext, nbp, bp, yprev, ylast,
                                                     ylens, pip, wsF, wsI);
    merge_kernel<<<NB, 256, 0, stream>>>(ext, nonext, blank, nbp, bp,
                                         yprev, ylast, ylens, pip, wsF, wsI, out);
}

// Round 5
// 126.080 us; speedup vs baseline: 1.3147x; 1.3147x over previous
//
#include <hip/hip_runtime.h>
#include <cstdint>
#include <cstddef>

#define NB 128      // N
#define KPP 32      // Kp
#define VV 2048     // V
#define SS 200      // S (tm1)
#define WID 32      // width == K
#define NEXT_BASE (KPP*VV)     // 65536
#define SLICES 16
#define KROWS 2
#define SCAND 4096
#define CAPA 512
#define NLIST (SLICES*WID + WID)   // 544

// output layout (flat f32, concat in return order)
#define SZ_YNEXT ((size_t)(SS+1)*NB*WID)               // 823296
#define NK       ((size_t)NB*WID)                      // 4096
#define O_LAST   (SZ_YNEXT)
#define O_LENS   (SZ_YNEXT + NK)
#define O_NB     (SZ_YNEXT + 2*NK)
#define O_B      (SZ_YNEXT + 3*NK)
#define O_PREF   (SZ_YNEXT + 4*NK)                     // size NB*WID*WID
#define O_SRC    (SZ_YNEXT + 4*NK + (size_t)NB*WID*WID)
#define O_NOEXT  (SZ_YNEXT + 5*NK + (size_t)NB*WID*WID)

__device__ __forceinline__ unsigned fkey(float f) {
    unsigned u = __float_as_uint(f);
    return (u & 0x80000000u) ? ~u : (u | 0x80000000u);
}
__device__ __forceinline__ float funkey(unsigned k) {
    unsigned u = (k & 0x80000000u) ? (k & 0x7FFFFFFFu) : ~k;
    return __uint_as_float(u);
}
__device__ __forceinline__ unsigned long long shflx64(unsigned long long v, int m) {
    int lo = __shfl_xor((int)(unsigned)v, m);
    int hi = __shfl_xor((int)(unsigned)(v >> 32), m);
    return ((unsigned long long)(unsigned)hi << 32) | (unsigned)lo;
}

// ---------------- kernel A: per-slice exact top-32, keys in registers ----------------
__global__ __launch_bounds__(256) void slice_topk_kernel(
    const float* __restrict__ ext,     // [N][Kp][V]
    const float* __restrict__ nbp_g,   // [N][Kp]
    const float* __restrict__ bp_g,    // [N][Kp]
    const int*   __restrict__ yprev,   // [S][N][Kp]
    const int*   __restrict__ ylast,   // [N][Kp]
    const int*   __restrict__ ylens,   // [N][Kp]
    const int*   __restrict__ pip,     // [N][Kp][Kp]
    unsigned* __restrict__ wsF, int* __restrict__ wsI)
{
    const int blk  = blockIdx.x;
    const int n    = blk >> 4;
    const int s    = blk & 15;
    const int k0   = s * KROWS;
    const int tid  = threadIdx.x;
    const int lane = tid & 63, wv = tid >> 6;

    __shared__ unsigned s_hist[256];
    __shared__ unsigned s_sfx[256];
    __shared__ int      s_last[KROWS];
    __shared__ float    s_nbp[KROWS], s_bp[KROWS];
    __shared__ unsigned s_hm[KROWS][VV/32];    // 512 B
    __shared__ int      s_bstar, s_cnt;
    __shared__ unsigned s_lf[CAPA];
    __shared__ int      s_li[CAPA];
    __shared__ int      s_part[2][4];

    // issue the 16 ext loads early (registers only, never LDS)
    const float4* g4 = (const float4*)(ext + ((size_t)n*KPP + k0)*VV);
    float4 f0 = g4[tid];
    float4 f1 = g4[tid + 256];
    float4 f2 = g4[tid + 512];
    float4 f3 = g4[tid + 768];

    if (tid < KROWS*(VV/32)) ((unsigned*)s_hm)[tid] = 0u;
    if (tid == 0) s_cnt = 0;
    if (tid < KROWS) {
        int k = k0 + tid;
        int last = ylast[n*KPP + k]; last = min(max(last, 0), VV-1);
        s_last[tid] = last;
        s_nbp[tid]  = nbp_g[n*KPP + k];
        s_bp[tid]   = bp_g[n*KPP + k];
    }
    __syncthreads();
    if (tid < KROWS*KPP) {     // has_match bits for this slice's 2 k-rows
        int lk = tid >> 5, j = tid & 31;
        int k = k0 + lk;
        int tlen = ylens[n*KPP + k];
        int tcl  = min(max(tlen, 0), SS-1);
        int tm   = yprev[((size_t)tcl*NB + n)*KPP + j];
        tm = min(max(tm, 0), VV-1);
        bool ex = (tlen + 1 == ylens[n*KPP + j]) && (pip[((size_t)n*KPP + k)*KPP + j] != 0);
        if (ex) atomicOr(&s_hm[lk][tm >> 5], 1u << (tm & 31));
    }
    __syncthreads();

    // 16 keys in registers; local cand idx q = 4*tid + j*1024 + e (j>>1 = k-row, compile-time)
    unsigned kreg[16];
    {
        const int   last0 = s_last[0], last1 = s_last[1];
        const float nbp0 = s_nbp[0], nbp1 = s_nbp[1];
        const float bp0  = s_bp[0],  bp1  = s_bp[1];
        const float fv[16] = {f0.x,f0.y,f0.z,f0.w, f1.x,f1.y,f1.z,f1.w,
                              f2.x,f2.y,f2.z,f2.w, f3.x,f3.y,f3.z,f3.w};
        #pragma unroll
        for (int j = 0; j < 4; ++j) {
            #pragma unroll
            for (int e = 0; e < 4; ++e) {
                const int lk = j >> 1;                 // compile-time
                int q = 4*tid + j*1024 + e;
                int v = q & (VV-1);
                float base = (v == (lk ? last1 : last0)) ? 0.0f : (lk ? nbp1 : nbp0);
                float val  = (base + (lk ? bp1 : bp0)) * fv[j*4 + e];
                if ((s_hm[lk][v >> 5] >> (v & 31)) & 1u) val = -INFINITY;
                kreg[j*4 + e] = fkey(val);
            }
        }
    }

    // ---- 8-bit histogram cascade from register keys ----
    unsigned pref = 0;
    int shift = 32, need = WID, c = 0;
    for (int lvl = 0; lvl < 4; ++lvl) {
        s_hist[tid] = 0u;
        __syncthreads();
        #pragma unroll
        for (int i = 0; i < 16; ++i) {
            unsigned kk = kreg[i];
            if (lvl == 0 || (kk >> shift) == pref)
                atomicAdd(&s_hist[(kk >> (shift - 8)) & 255], 1u);
        }
        __syncthreads();
        s_sfx[tid] = s_hist[tid];
        __syncthreads();
        for (int off = 1; off < 256; off <<= 1) {      // inclusive suffix scan
            unsigned add = (tid + off < 256) ? s_sfx[tid + off] : 0u;
            __syncthreads();
            s_sfx[tid] += add;
            __syncthreads();
        }
        {
            int inc   = (int)s_sfx[tid];
            int above = (tid == 255) ? 0 : (int)s_sfx[tid + 1];
            if (above < need && need <= inc) s_bstar = tid;   // unique crossing
        }
        __syncthreads();
        int bstar = s_bstar;
        int G     = (bstar == 255) ? 0 : (int)s_sfx[bstar + 1];
        int bcnt  = (int)s_hist[bstar];
        pref  = (pref << 8) | (unsigned)bstar;
        shift -= 8;
        need -= G;
        c = (WID - need) + bcnt;     // #{kk : (kk>>shift) >= pref}
        if (c <= CAPA || shift == 0) break;
        __syncthreads();             // protect hist/sfx reuse
    }

    if (c <= CAPA) {
        // gather survivors from registers
        #pragma unroll
        for (int i = 0; i < 16; ++i) {
            unsigned kk = kreg[i];
            bool sel = (shift == 0) ? (kk >= pref) : ((kk >> shift) >= pref);
            if (sel) {
                int q = 4*tid + (i >> 2)*1024 + (i & 3);
                int slot = atomicAdd(&s_cnt, 1);
                s_lf[slot] = kk; s_li[slot] = (k0 << 11) + q;
            }
        }
        __syncthreads();
    } else {
        // pathological: shift==0, pref == exact key T; pick `need` smallest-q ties
        const unsigned T = pref;
        int pp = 0;
        unsigned istar = 0;
        for (int b = 11; b >= 0; --b) {
            int cnt = 0;
            #pragma unroll
            for (int i = 0; i < 16; ++i) {
                unsigned kk = kreg[i];
                unsigned q = (unsigned)(4*tid + (i >> 2)*1024 + (i & 3));
                if (kk == T && (q >> (b+1)) == (istar >> (b+1)) && !((q >> b) & 1u)) cnt++;
            }
            #pragma unroll
            for (int off = 32; off; off >>= 1) cnt += __shfl_xor(cnt, off);
            if (lane == 0) s_part[pp][wv] = cnt;
            __syncthreads();
            int tot = s_part[pp][0] + s_part[pp][1] + s_part[pp][2] + s_part[pp][3];
            pp ^= 1;
            if (tot >= need) { } else { need -= tot; istar |= (1u << b); }
        }
        #pragma unroll
        for (int i = 0; i < 16; ++i) {
            unsigned kk = kreg[i];
            unsigned q = (unsigned)(4*tid + (i >> 2)*1024 + (i & 3));
            if (kk > T || (kk == T && q <= istar)) {
                int slot = atomicAdd(&s_cnt, 1);
                s_lf[slot] = kk; s_li[slot] = (k0 << 11) + (int)q;
            }
        }
        __syncthreads();
    }
    const int cc = s_cnt;

    // rank-sort survivors (broadcast LDS reads), write slice top-32
    for (int e = tid; e < cc; e += 256) {
        unsigned mf = s_lf[e]; int mi = s_li[e];
        int rank = 0;
        for (int j2 = 0; j2 < cc; ++j2) {
            unsigned f = s_lf[j2];
            rank += (f > mf || (f == mf && s_li[j2] < mi)) ? 1 : 0;
        }
        if (rank < WID) { wsF[blk*WID + rank] = mf; wsI[blk*WID + rank] = mi; }
    }
}

// ---------------- kernel B: merge (tau-filtered) + epilogue + y_next + prefix ----------------
__global__ __launch_bounds__(256) void merge_kernel(
    const float* __restrict__ ext,
    const float* __restrict__ nonext,
    const float* __restrict__ blank,
    const float* __restrict__ nbp_g,
    const float* __restrict__ bp_g,
    const int*   __restrict__ yprev,
    const int*   __restrict__ ylast,
    const int*   __restrict__ ylens,
    const int*   __restrict__ pip,
    const unsigned* __restrict__ wsF, const int* __restrict__ wsI,
    float* __restrict__ out)
{
    const int n   = blockIdx.x;
    const int tid = threadIdx.x;

    __shared__ int      s_last[KPP];
    __shared__ float    s_nbp[KPP], s_bp[KPP], s_bne[KPP], s_nbne[KPP];
    __shared__ int      s_tm[KPP][KPP];
    __shared__ unsigned s_exact[KPP];
    __shared__ unsigned s_cf[NLIST];
    __shared__ int      s_ci[NLIST];
    __shared__ unsigned s_ff[NLIST];
    __shared__ int      s_fi[NLIST];
    __shared__ unsigned long long s_tau;
    __shared__ int      s_cnt;
    __shared__ int      s_selidx[WID];
    __shared__ float    s_selval[WID];
    __shared__ int      s_r_src[WID], s_r_lens[WID], s_r_ext[WID], s_r_noext[WID];

    if (tid == 0) s_cnt = 0;
    if (tid < KPP) {
        int k = tid;
        s_exact[k] = 0u;
        int last = ylast[n*KPP + k]; last = min(max(last, 0), VV-1);
        float a = nbp_g[n*KPP + k], b = bp_g[n*KPP + k];
        s_last[k] = last; s_nbp[k] = a; s_bp[k] = b;
        s_bne[k]  = (a + b) * blank[n];
        s_nbne[k] = a * nonext[(size_t)n*VV + last];
    }
    __syncthreads();
    for (int i = tid; i < KPP*KPP; i += 256) {   // (k,j) pairs
        int k = i >> 5, j = i & 31;
        int tlen = ylens[n*KPP + k];
        int tcl  = min(max(tlen, 0), SS-1);
        int tm   = yprev[((size_t)tcl*NB + n)*KPP + j];
        tm = min(max(tm, 0), VV-1);
        s_tm[k][j] = tm;
        bool ex = (tlen + 1 == ylens[n*KPP + j]) && (pip[((size_t)n*KPP + k)*KPP + j] != 0);
        if (ex) atomicOr(&s_exact[k], 1u << j);
    }
    __syncthreads();
    if (tid < KPP) {    // absorb (deterministic k-order)
        int j = tid;
        float acc = s_nbne[j];
        for (int k = 0; k < KPP; ++k) {
            if ((s_exact[k] >> j) & 1u) {
                int v = s_tm[k][j];
                float base = (v == s_last[k]) ? 0.0f : s_nbp[k];
                acc += (base + s_bp[k]) * ext[((size_t)n*KPP + k)*VV + v];
            }
        }
        s_nbne[j] = acc;
    }
    __syncthreads();

    // merge list: 512 slice winners + 32 nonext
    for (int i = tid; i < NLIST; i += 256) {
        if (i < SLICES*WID) {
            s_cf[i] = wsF[n*SLICES*WID + i];
            s_ci[i] = wsI[n*SLICES*WID + i];
        } else {
            int j = i - SLICES*WID;
            s_cf[i] = fkey(s_nbne[j] + s_bne[j]);
            s_ci[i] = NEXT_BASE + j;
        }
    }
    __syncthreads();

    // tau = max over slices of that slice's 32nd packed key (lower bound on global 32nd)
    if (tid < 64) {
        unsigned long long p = 0ull;
        if (tid < SLICES) {
            int i = tid*WID + (WID-1);
            p = ((unsigned long long)s_cf[i] << 32) | (unsigned)(~s_ci[i]);
        }
        #pragma unroll
        for (int off = 32; off; off >>= 1) {
            unsigned long long o = shflx64(p, off);
            if (o > p) p = o;
        }
        if (tid == 0) s_tau = p;
    }
    __syncthreads();
    const unsigned long long tau = s_tau;

    // filter + gather (expected ~35 survivors)
    for (int i = tid; i < NLIST; i += 256) {
        unsigned long long p = ((unsigned long long)s_cf[i] << 32) | (unsigned)(~s_ci[i]);
        if (p >= tau) {
            int slot = atomicAdd(&s_cnt, 1);
            s_ff[slot] = s_cf[i]; s_fi[slot] = s_ci[i];
        }
    }
    __syncthreads();
    const int cc = s_cnt;

    // exact rank among filtered; rank<32 = output position
    for (int e = tid; e < cc; e += 256) {
        unsigned mf = s_ff[e]; int mi = s_fi[e];
        int rank = 0;
        for (int j = 0; j < cc; ++j) {
            unsigned f = s_ff[j];
            rank += (f > mf || (f == mf && s_fi[j] < mi)) ? 1 : 0;
        }
        if (rank < WID) { s_selidx[rank] = mi; s_selval[rank] = funkey(mf); }
    }
    __syncthreads();

    // epilogue: per-k scalar outputs
    if (tid < WID) {
        int k = tid;
        int ind = s_selidx[k];
        bool noext = ind >= NEXT_BASE;
        int src  = noext ? (ind - NEXT_BASE) : (ind >> 11);
        int extk = ind & (VV-1);
        int plen = ylens[n*KPP + src];
        int lens = plen + (noext ? 0 : 1);
        float nbv = noext ? s_nbne[src] : s_selval[k];
        float bv  = noext ? s_bne[src]  : 0.0f;
        int lastv = noext ? s_last[src] : extk;
        size_t o = (size_t)n*WID + k;
        out[O_LAST  + o] = (float)lastv;
        out[O_LENS  + o] = (float)lens;
        out[O_NB    + o] = nbv;
        out[O_B     + o] = bv;
        out[O_SRC   + o] = (float)src;
        out[O_NOEXT + o] = noext ? 1.0f : 0.0f;
        s_r_src[k] = src; s_r_lens[k] = lens; s_r_ext[k] = extk;
        s_r_noext[k] = noext ? 1 : 0;
    }
    __syncthreads();

    // fused next_is_prefix
    for (int i = tid; i < WID*WID; i += 256) {
        int k = i >> 5, j = i & 31;
        int src_j = s_r_src[j];
        int no_k  = s_r_noext[k], no_j = s_r_noext[j];
        int lens_k = s_r_lens[k], lens_j = s_r_lens[j];
        int plen_j = lens_j - (no_j ? 0 : 1);
        bool prefix = pip[((size_t)n*KPP + s_r_src[k])*KPP + src_j] != 0;
        bool leq    = lens_k <= lens_j;
        int  tstar  = max(lens_k - 1, 0);
        int  tmj;
        if (tstar == plen_j)   tmj = s_r_ext[j];
        else if (tstar < SS)   tmj = yprev[((size_t)tstar*NB + n)*KPP + src_j];
        else                   tmj = 0;
        bool res = prefix && leq && (no_k || (tmj == s_r_ext[k]));
        out[O_PREF + (size_t)n*WID*WID + i] = res ? 1.0f : 0.0f;
    }

    // fused y_next: out[t][n][k]
    for (int id = tid; id < (SS+1)*WID; id += 256) {
        int t = id >> 5, k = id & 31;
        int src  = s_r_src[k];
        int plen = s_r_lens[k] - (s_r_noext[k] ? 0 : 1);
        float val;
        if (t == plen)   val = (float)s_r_ext[k];
        else if (t < SS) val = (float)yprev[((size_t)t*NB + n)*KPP + src];
        else             val = 0.0f;
        out[(size_t)t*NK + (size_t)n*WID + k] = val;
    }
}

extern "C" void kernel_launch(void* const* d_in, const int* in_sizes, int n_in,
                              void* d_out, int out_size, void* d_ws, size_t ws_size,
                              hipStream_t stream) {
    const float* ext    = (const float*)d_in[0];
    const float* nonext = (const float*)d_in[1];
    const float* blank  = (const float*)d_in[2];
    const float* nbp    = (const float*)d_in[3];
    const float* bp     = (const float*)d_in[4];
    const int*   yprev  = (const int*)d_in[5];
    const int*   ylast  = (const int*)d_in[6];
    const int*   ylens  = (const int*)d_in[7];
    const int*   pip    = (const int*)d_in[8];
    float* out = (float*)d_out;

    unsigned* wsF = (unsigned*)d_ws;                     // 2048*32 u32
    int*      wsI = (int*)d_ws + NB*SLICES*WID;          // 2048*32 i32

    slice_topk_kernel<<<NB*SLICES, 256, 0, stream>>>(ext, nbp, bp, yprev, ylast,
                                                     ylens, pip, wsF, wsI);
    merge_kernel<<<NB, 256, 0, stream>>>(ext, nonext, blank, nbp, bp,
                                         yprev, ylast, ylens, pip, wsF, wsI, out);
}

// Round 7
// 56.877 us; speedup vs baseline: 2.9144x; 2.2167x over previous
//
#include <hip/hip_runtime.h>
#include <cstdint>
#include <cstddef>

#define NB 128      // N
#define KPP 32      // Kp
#define VV 2048     // V
#define SS 200      // S (tm1)
#define WID 32      // width == K
#define NEXT_BASE (KPP*VV)     // 65536
#define WPB 4                  // waves per block (one k-row per wave)
#define KBLK (KPP/WPB)         // 8 blocks per n
#define CAPW 128               // per-wave survivor cap
#define NLIST (KBLK*WID + WID) // 288 merge candidates

// output layout (flat f32, concat in return order)
#define SZ_YNEXT ((size_t)(SS+1)*NB*WID)               // 823296
#define NK       ((size_t)NB*WID)                      // 4096
#define O_LAST   (SZ_YNEXT)
#define O_LENS   (SZ_YNEXT + NK)
#define O_NB     (SZ_YNEXT + 2*NK)
#define O_B      (SZ_YNEXT + 3*NK)
#define O_PREF   (SZ_YNEXT + 4*NK)                     // size NB*WID*WID
#define O_SRC    (SZ_YNEXT + 4*NK + (size_t)NB*WID*WID)
#define O_NOEXT  (SZ_YNEXT + 5*NK + (size_t)NB*WID*WID)

__device__ __forceinline__ unsigned fkey(float f) {
    unsigned u = __float_as_uint(f);
    return (u & 0x80000000u) ? ~u : (u | 0x80000000u);
}
__device__ __forceinline__ float funkey(unsigned k) {
    unsigned u = (k & 0x80000000u) ? (k & 0x7FFFFFFFu) : ~k;
    return __uint_as_float(u);
}
__device__ __forceinline__ unsigned long long shflx64(unsigned long long v, int m) {
    int lo = __shfl_xor((int)(unsigned)v, m);
    int hi = __shfl_xor((int)(unsigned)(v >> 32), m);
    return ((unsigned long long)(unsigned)hi << 32) | (unsigned)lo;
}

// ---------------- kernel A: one wave per k-row, exact top-32, block-merged ----------------
__global__ __launch_bounds__(256) void slice_topk_kernel(
    const float* __restrict__ ext,     // [N][Kp][V]
    const float* __restrict__ nbp_g,   // [N][Kp]
    const float* __restrict__ bp_g,    // [N][Kp]
    const int*   __restrict__ yprev,   // [S][N][Kp]
    const int*   __restrict__ ylast,   // [N][Kp]
    const int*   __restrict__ ylens,   // [N][Kp]
    const int*   __restrict__ pip,     // [N][Kp][Kp]
    unsigned* __restrict__ wsF, int* __restrict__ wsI)
{
    const int blk  = blockIdx.x;
    const int n    = blk >> 3;          // KBLK = 8
    const int kb   = blk & 7;
    const int tid  = threadIdx.x;
    const int w    = tid >> 6;
    const int lane = tid & 63;
    const int k    = kb*WPB + w;

    __shared__ unsigned s_hm[WPB][VV/32];   // 1 KB, wave-private rows
    __shared__ unsigned s_bk[WPB][CAPW];    // wave-private survivor buffers
    __shared__ int      s_bi[WPB][CAPW];
    __shared__ unsigned s_mk[WPB*WID];      // block-merge candidates (128)
    __shared__ int      s_mi[WPB*WID];

    // per-row params (wave-uniform addresses -> broadcast loads)
    const int   tlen = ylens[n*KPP + k];
    int last = ylast[n*KPP + k]; last = min(max(last, 0), VV-1);
    const float nbp = nbp_g[n*KPP + k];
    const float bp  = bp_g[n*KPP + k];

    s_hm[w][lane] = 0u;                 // VV/32 == 64 == lane count

    // issue the 8 float4 loads early (32 floats/lane, registers only)
    const float4* g4 = (const float4*)(ext + ((size_t)n*KPP + k)*VV);
    float4 f[8];
    #pragma unroll
    for (int j = 0; j < 8; ++j) f[j] = g4[lane + 64*j];

    // has-match bits for this k-row (wave-private LDS, same-wave ordering)
    if (lane < KPP) {
        int j = lane;
        int tcl = min(max(tlen, 0), SS-1);
        int tm  = yprev[((size_t)tcl*NB + n)*KPP + j];
        tm = min(max(tm, 0), VV-1);
        bool ex = (tlen + 1 == ylens[n*KPP + j]) && (pip[((size_t)n*KPP + k)*KPP + j] != 0);
        if (ex) atomicOr(&s_hm[w][tm >> 5], 1u << (tm & 31));
    }

    // 32 keys in registers; v = 4*lane + 256*j + e
    unsigned key[32];
    #pragma unroll
    for (int j = 0; j < 8; ++j) {
        const float fe[4] = {f[j].x, f[j].y, f[j].z, f[j].w};
        #pragma unroll
        for (int e = 0; e < 4; ++e) {
            int v = 4*lane + 256*j + e;
            float base = (v == last) ? 0.0f : nbp;
            float val  = (base + bp) * fe[e];
            if ((s_hm[w][v >> 5] >> (v & 31)) & 1u) val = -INFINITY;
            key[j*4 + e] = fkey(val);
        }
    }

    // per-lane max, then 64-lane bitonic ascending sort of the maxima
    unsigned m = key[0];
    #pragma unroll
    for (int i = 1; i < 32; ++i) m = max(m, key[i]);
    unsigned sv = m;
    for (int kk = 2; kk <= 64; kk <<= 1)
        for (int j = kk >> 1; j > 0; j >>= 1) {
            unsigned o = (unsigned)__shfl_xor((int)sv, j);
            bool up = ((lane & kk) == 0);
            bool keepMax = (((lane & j) != 0) == up);
            sv = keepMax ? max(sv, o) : min(sv, o);
        }
    const unsigned tau = (unsigned)__shfl((int)sv, 32);   // 32nd-largest lane-max

    // survivor count
    int cnt = 0;
    #pragma unroll
    for (int i = 0; i < 32; ++i) cnt += (key[i] >= tau) ? 1 : 0;
    int c = cnt;
    #pragma unroll
    for (int off = 32; off; off >>= 1) c += __shfl_xor(c, off);

    const bool normal = (c >= WID && c <= CAPW);
    unsigned T = 0, istar = 0;
    if (!normal) {
        // exact fallback: key-bit radix, then idx radix among ties (shuffle-only)
        int need = WID;
        unsigned prefix = 0;
        for (int b = 31; b >= 0; --b) {
            unsigned pb1 = (prefix >> b) | 1u;
            int c1 = 0;
            #pragma unroll
            for (int i = 0; i < 32; ++i) c1 += ((key[i] >> b) == pb1) ? 1 : 0;
            #pragma unroll
            for (int off = 32; off; off >>= 1) c1 += __shfl_xor(c1, off);
            if (c1 >= need) prefix |= (1u << b);
            else need -= c1;
        }
        T = prefix;
        for (int b = 10; b >= 0; --b) {
            int c0 = 0;
            #pragma unroll
            for (int i = 0; i < 32; ++i) {
                unsigned vv = (unsigned)(4*lane + 256*(i >> 2) + (i & 3));
                if (key[i] == T && (vv >> (b+1)) == (istar >> (b+1)) && !((vv >> b) & 1u)) c0++;
            }
            #pragma unroll
            for (int off = 32; off; off >>= 1) c0 += __shfl_xor(c0, off);
            if (c0 >= need) { } else { need -= c0; istar |= (1u << b); }
        }
    }

    // gather survivors via shuffle-scan into wave-private LDS
    int mycnt = 0;
    #pragma unroll
    for (int i = 0; i < 32; ++i) {
        unsigned vv = (unsigned)(4*lane + 256*(i >> 2) + (i & 3));
        bool sel = normal ? (key[i] >= tau)
                          : (key[i] > T || (key[i] == T && vv <= istar));
        if (sel) mycnt++;
    }
    int sc = mycnt;
    for (int off = 1; off < 64; off <<= 1) {
        int o = __shfl_up(sc, off);
        if (lane >= off) sc += o;
    }
    int base  = sc - mycnt;
    int total = __shfl(sc, 63);
    int off2  = base;
    #pragma unroll
    for (int i = 0; i < 32; ++i) {
        unsigned vv = (unsigned)(4*lane + 256*(i >> 2) + (i & 3));
        bool sel = normal ? (key[i] >= tau)
                          : (key[i] > T || (key[i] == T && vv <= istar));
        if (sel && off2 < CAPW) { s_bk[w][off2] = key[i]; s_bi[w][off2] = (int)vv; off2++; }
    }

    // in-wave rank of survivors; rank<32 -> wave's sorted top-32
    for (int e = lane; e < total; e += 64) {
        unsigned mf = s_bk[w][e]; int mi = s_bi[w][e];
        int rank = 0;
        for (int j2 = 0; j2 < total; ++j2) {
            unsigned fq = s_bk[w][j2];
            rank += (fq > mf || (fq == mf && s_bi[w][j2] < mi)) ? 1 : 0;
        }
        if (rank < WID) { s_mk[w*WID + rank] = mf; s_mi[w*WID + rank] = (k << 11) + mi; }
    }
    __syncthreads();

    // block merge: exact rank of 128 wave-winners -> block top-32
    if (tid < WPB*WID) {
        unsigned mf = s_mk[tid]; int mi = s_mi[tid];
        int rank = 0;
        for (int j2 = 0; j2 < WPB*WID; ++j2) {
            unsigned fq = s_mk[j2];
            rank += (fq > mf || (fq == mf && s_mi[j2] < mi)) ? 1 : 0;
        }
        if (rank < WID) { wsF[blk*WID + rank] = mf; wsI[blk*WID + rank] = mi; }
    }
}

// ---------------- kernel B: merge (tau-filtered) + epilogue + prefix ----------------
__global__ __launch_bounds__(256) void merge_kernel(
    const float* __restrict__ ext,
    const float* __restrict__ nonext,
    const float* __restrict__ blank,
    const float* __restrict__ nbp_g,
    const float* __restrict__ bp_g,
    const int*   __restrict__ yprev,
    const int*   __restrict__ ylast,
    const int*   __restrict__ ylens,
    const int*   __restrict__ pip,
    const unsigned* __restrict__ wsF, const int* __restrict__ wsI,
    float* __restrict__ out)
{
    const int n   = blockIdx.x;
    const int tid = threadIdx.x;

    __shared__ int      s_last[KPP];
    __shared__ float    s_nbp[KPP], s_bp[KPP], s_bne[KPP], s_nbne[KPP];
    __shared__ int      s_tm[KPP][KPP];
    __shared__ unsigned s_exact[KPP];
    __shared__ unsigned s_cf[NLIST];
    __shared__ int      s_ci[NLIST];
    __shared__ unsigned s_ff[NLIST];
    __shared__ int      s_fi[NLIST];
    __shared__ unsigned long long s_tau;
    __shared__ int      s_cnt;
    __shared__ int      s_selidx[WID];
    __shared__ float    s_selval[WID];
    __shared__ int      s_r_src[WID], s_r_lens[WID], s_r_ext[WID], s_r_noext[WID];

    if (tid == 0) s_cnt = 0;
    if (tid < KPP) {
        int k = tid;
        s_exact[k] = 0u;
        int last = ylast[n*KPP + k]; last = min(max(last, 0), VV-1);
        float a = nbp_g[n*KPP + k], b = bp_g[n*KPP + k];
        s_last[k] = last; s_nbp[k] = a; s_bp[k] = b;
        s_bne[k]  = (a + b) * blank[n];
        s_nbne[k] = a * nonext[(size_t)n*VV + last];
    }
    __syncthreads();
    for (int i = tid; i < KPP*KPP; i += 256) {   // (k,j) pairs: to_match + exact bits
        int k = i >> 5, j = i & 31;
        int tlen = ylens[n*KPP + k];
        int tcl  = min(max(tlen, 0), SS-1);
        int tm   = yprev[((size_t)tcl*NB + n)*KPP + j];
        tm = min(max(tm, 0), VV-1);
        s_tm[k][j] = tm;
        bool ex = (tlen + 1 == ylens[n*KPP + j]) && (pip[((size_t)n*KPP + k)*KPP + j] != 0);
        if (ex) atomicOr(&s_exact[k], 1u << j);
    }
    __syncthreads();
    if (tid < KPP) {    // absorb (serial k-order: bit-exact vs reference)
        int j = tid;
        float acc = s_nbne[j];
        for (int k = 0; k < KPP; ++k) {
            if ((s_exact[k] >> j) & 1u) {
                int v = s_tm[k][j];
                float base = (v == s_last[k]) ? 0.0f : s_nbp[k];
                acc += (base + s_bp[k]) * ext[((size_t)n*KPP + k)*VV + v];
            }
        }
        s_nbne[j] = acc;
    }
    __syncthreads();

    // merge list: 256 block winners + 32 nonext
    for (int i = tid; i < NLIST; i += 256) {
        if (i < KBLK*WID) {
            s_cf[i] = wsF[n*KBLK*WID + i];
            s_ci[i] = wsI[n*KBLK*WID + i];
        } else {
            int j = i - KBLK*WID;
            s_cf[i] = fkey(s_nbne[j] + s_bne[j]);
            s_ci[i] = NEXT_BASE + j;
        }
    }
    __syncthreads();

    // tau = max over blocks of their 32nd packed key (lower bound on global 32nd)
    if (tid < 64) {
        unsigned long long p = 0ull;
        if (tid < KBLK) {
            int i = tid*WID + (WID-1);
            p = ((unsigned long long)s_cf[i] << 32) | (unsigned)(~s_ci[i]);
        }
        #pragma unroll
        for (int off = 32; off; off >>= 1) {
            unsigned long long o = shflx64(p, off);
            if (o > p) p = o;
        }
        if (tid == 0) s_tau = p;
    }
    __syncthreads();
    const unsigned long long tau = s_tau;

    for (int i = tid; i < NLIST; i += 256) {
        unsigned long long p = ((unsigned long long)s_cf[i] << 32) | (unsigned)(~s_ci[i]);
        if (p >= tau) {
            int slot = atomicAdd(&s_cnt, 1);
            s_ff[slot] = s_cf[i]; s_fi[slot] = s_ci[i];
        }
    }
    __syncthreads();
    const int cc = s_cnt;

    for (int e = tid; e < cc; e += 256) {
        unsigned mf = s_ff[e]; int mi = s_fi[e];
        int rank = 0;
        for (int j = 0; j < cc; ++j) {
            unsigned f = s_ff[j];
            rank += (f > mf || (f == mf && s_fi[j] < mi)) ? 1 : 0;
        }
        if (rank < WID) { s_selidx[rank] = mi; s_selval[rank] = funkey(mf); }
    }
    __syncthreads();

    // epilogue: per-k scalar outputs
    if (tid < WID) {
        int k = tid;
        int ind = s_selidx[k];
        bool noext = ind >= NEXT_BASE;
        int src  = noext ? (ind - NEXT_BASE) : (ind >> 11);
        int extk = ind & (VV-1);
        int plen = ylens[n*KPP + src];
        int lens = plen + (noext ? 0 : 1);
        float nbv = noext ? s_nbne[src] : s_selval[k];
        float bv  = noext ? s_bne[src]  : 0.0f;
        int lastv = noext ? s_last[src] : extk;
        size_t o = (size_t)n*WID + k;
        out[O_LAST  + o] = (float)lastv;
        out[O_LENS  + o] = (float)lens;
        out[O_NB    + o] = nbv;
        out[O_B     + o] = bv;
        out[O_SRC   + o] = (float)src;
        out[O_NOEXT + o] = noext ? 1.0f : 0.0f;
        s_r_src[k] = src; s_r_lens[k] = lens; s_r_ext[k] = extk;
        s_r_noext[k] = noext ? 1 : 0;
    }
    __syncthreads();

    // fused next_is_prefix (all 1024 (k,j) pairs with 256 threads)
    for (int i = tid; i < WID*WID; i += 256) {
        int k = i >> 5, j = i & 31;
        int src_j = s_r_src[j];
        int no_k  = s_r_noext[k], no_j = s_r_noext[j];
        int lens_k = s_r_lens[k], lens_j = s_r_lens[j];
        int plen_j = lens_j - (no_j ? 0 : 1);
        bool prefix = pip[((size_t)n*KPP + s_r_src[k])*KPP + src_j] != 0;
        bool leq    = lens_k <= lens_j;
        int  tstar  = max(lens_k - 1, 0);
        int  tmj;
        if (tstar == plen_j)   tmj = s_r_ext[j];
        else if (tstar < SS)   tmj = yprev[((size_t)tstar*NB + n)*KPP + src_j];
        else                   tmj = 0;
        bool res = prefix && leq && (no_k || (tmj == s_r_ext[k]));
        out[O_PREF + (size_t)n*WID*WID + i] = res ? 1.0f : 0.0f;
    }
}

// ---------------- kernel C: y_next (full-chip) ----------------
__global__ void ynext_kernel(const int* __restrict__ yprev, float* __restrict__ out) {
    int id = blockIdx.x*blockDim.x + threadIdx.x;
    if (id >= (int)SZ_YNEXT) return;
    int k = id & 31;
    int n = (id >> 5) & 127;
    int t = id >> 12;                    // NB*WID = 4096 = 2^12
    size_t o = (size_t)n*WID + k;
    int src    = (int)out[O_SRC + o];
    bool noext = out[O_NOEXT + o] != 0.0f;
    int lens   = (int)out[O_LENS + o];
    int plen   = lens - (noext ? 0 : 1);
    int extk   = noext ? src : (int)out[O_LAST + o];
    float val;
    if (t == plen)      val = (float)extk;
    else if (t < SS)    val = (float)yprev[((size_t)t*NB + n)*KPP + src];
    else                val = 0.0f;
    out[id] = val;
}

extern "C" void kernel_launch(void* const* d_in, const int* in_sizes, int n_in,
                              void* d_out, int out_size, void* d_ws, size_t ws_size,
                              hipStream_t stream) {
    const float* ext    = (const float*)d_in[0];
    const float* nonext = (const float*)d_in[1];
    const float* blank  = (const float*)d_in[2];
    const float* nbp    = (const float*)d_in[3];
    const float* bp     = (const float*)d_in[4];
    const int*   yprev  = (const int*)d_in[5];
    const int*   ylast  = (const int*)d_in[6];
    const int*   ylens  = (const int*)d_in[7];
    const int*   pip    = (const int*)d_in[8];
    float* out = (float*)d_out;

    unsigned* wsF = (unsigned*)d_ws;                       // NB*KBLK*WID u32
    int*      wsI = (int*)d_ws + NB*KBLK*WID;

    slice_topk_kernel<<<NB*KBLK, 256, 0, stream>>>(ext, nbp, bp, yprev, ylast,
                                                   ylens, pip, wsF, wsI);
    merge_kernel<<<NB, 256, 0, stream>>>(ext, nonext, blank, nbp, bp,
                                         yprev, ylast, ylens, pip, wsF, wsI, out);
    ynext_kernel<<<((int)SZ_YNEXT + 255)/256, 256, 0, stream>>>(yprev, out);
}

// Round 8
// 56.859 us; speedup vs baseline: 2.9153x; 1.0003x over previous
//
#include <hip/hip_runtime.h>
#include <cstdint>
#include <cstddef>

#define NB 128      // N
#define KPP 32      // Kp
#define VV 2048     // V
#define SS 200      // S (tm1)
#define WID 32      // width == K
#define NEXT_BASE (KPP*VV)     // 65536
#define ROWS_PB 2              // k-rows per block (2 waves per row)
#define KBLK 16                // blocks per n
#define CAPW 128               // per-wave survivor cap
#define NLIST (KBLK*WID + WID) // 544 merge candidates

// output layout (flat f32, concat in return order)
#define SZ_YNEXT ((size_t)(SS+1)*NB*WID)               // 823296
#define NK       ((size_t)NB*WID)                      // 4096
#define O_LAST   (SZ_YNEXT)
#define O_LENS   (SZ_YNEXT + NK)
#define O_NB     (SZ_YNEXT + 2*NK)
#define O_B      (SZ_YNEXT + 3*NK)
#define O_PREF   (SZ_YNEXT + 4*NK)                     // size NB*WID*WID
#define O_SRC    (SZ_YNEXT + 4*NK + (size_t)NB*WID*WID)
#define O_NOEXT  (SZ_YNEXT + 5*NK + (size_t)NB*WID*WID)

__device__ __forceinline__ unsigned fkey(float f) {
    unsigned u = __float_as_uint(f);
    return (u & 0x80000000u) ? ~u : (u | 0x80000000u);
}
__device__ __forceinline__ float funkey(unsigned k) {
    unsigned u = (k & 0x80000000u) ? (k & 0x7FFFFFFFu) : ~k;
    return __uint_as_float(u);
}
__device__ __forceinline__ unsigned long long shflx64(unsigned long long v, int m) {
    int lo = __shfl_xor((int)(unsigned)v, m);
    int hi = __shfl_xor((int)(unsigned)(v >> 32), m);
    return ((unsigned long long)(unsigned)hi << 32) | (unsigned)lo;
}

// ---------------- kernel A: one wave per HALF k-row, exact top-32, block-merged ----------------
__global__ __launch_bounds__(256) void slice_topk_kernel(
    const float* __restrict__ ext,     // [N][Kp][V]
    const float* __restrict__ nbp_g,   // [N][Kp]
    const float* __restrict__ bp_g,    // [N][Kp]
    const int*   __restrict__ yprev,   // [S][N][Kp]
    const int*   __restrict__ ylast,   // [N][Kp]
    const int*   __restrict__ ylens,   // [N][Kp]
    const int*   __restrict__ pip,     // [N][Kp][Kp]
    unsigned* __restrict__ wsF, int* __restrict__ wsI)
{
    const int blk  = blockIdx.x;
    const int n    = blk >> 4;          // KBLK = 16
    const int kb   = blk & 15;
    const int tid  = threadIdx.x;
    const int w    = tid >> 6;          // 4 waves
    const int lane = tid & 63;
    const int k    = kb*ROWS_PB + (w >> 1);
    const int half = w & 1;

    __shared__ unsigned s_hm[4][VV/32];     // per-wave private hm (full row), 1 KB
    __shared__ unsigned s_bk[4][CAPW];      // wave-private survivor buffers
    __shared__ int      s_bi[4][CAPW];
    __shared__ unsigned s_mk[4*WID];        // block-merge candidates (128)
    __shared__ int      s_mi[4*WID];

    // per-row params (wave-uniform addresses -> broadcast loads)
    const int   tlen = ylens[n*KPP + k];
    int last = ylast[n*KPP + k]; last = min(max(last, 0), VV-1);
    const float nbp = nbp_g[n*KPP + k];
    const float bp  = bp_g[n*KPP + k];

    s_hm[w][lane] = 0u;                 // VV/32 == 64 == lane count

    // issue the 4 float4 loads early (16 floats/lane, registers only)
    const float4* g4 = (const float4*)(ext + ((size_t)n*KPP + k)*VV + half*1024);
    float4 f[4];
    #pragma unroll
    for (int j = 0; j < 4; ++j) f[j] = g4[lane + 64*j];

    // has-match bits for this k-row (wave-private LDS, same-wave ordering)
    if (lane < KPP) {
        int j = lane;
        int tcl = min(max(tlen, 0), SS-1);
        int tm  = yprev[((size_t)tcl*NB + n)*KPP + j];
        tm = min(max(tm, 0), VV-1);
        bool ex = (tlen + 1 == ylens[n*KPP + j]) && (pip[((size_t)n*KPP + k)*KPP + j] != 0);
        if (ex) atomicOr(&s_hm[w][tm >> 5], 1u << (tm & 31));
    }

    // 16 keys in registers; v_local = 4*lane + 256*j + e in [0,1024)
    unsigned key[16];
    #pragma unroll
    for (int j = 0; j < 4; ++j) {
        const float fe[4] = {f[j].x, f[j].y, f[j].z, f[j].w};
        #pragma unroll
        for (int e = 0; e < 4; ++e) {
            int vl = 4*lane + 256*j + e;
            int v  = (half << 10) + vl;            // full-row v for hm/last checks
            float base = (v == last) ? 0.0f : nbp;
            float val  = (base + bp) * fe[e];
            if ((s_hm[w][v >> 5] >> (v & 31)) & 1u) val = -INFINITY;
            key[j*4 + e] = fkey(val);
        }
    }

    // per-lane max, then 64-lane bitonic ascending sort of the maxima
    unsigned m = key[0];
    #pragma unroll
    for (int i = 1; i < 16; ++i) m = max(m, key[i]);
    unsigned sv = m;
    for (int kk = 2; kk <= 64; kk <<= 1)
        for (int j = kk >> 1; j > 0; j >>= 1) {
            unsigned o = (unsigned)__shfl_xor((int)sv, j);
            bool up = ((lane & kk) == 0);
            bool keepMax = (((lane & j) != 0) == up);
            sv = keepMax ? max(sv, o) : min(sv, o);
        }
    const unsigned tau = (unsigned)__shfl((int)sv, 32);   // 32nd-largest lane-max

    // survivor count
    int cnt = 0;
    #pragma unroll
    for (int i = 0; i < 16; ++i) cnt += (key[i] >= tau) ? 1 : 0;
    int c = cnt;
    #pragma unroll
    for (int off = 32; off; off >>= 1) c += __shfl_xor(c, off);

    const bool normal = (c >= WID && c <= CAPW);
    unsigned T = 0, istar = 0;
    if (!normal) {
        // exact fallback: key-bit radix, then idx radix among ties (shuffle-only)
        int need = WID;
        unsigned prefix = 0;
        for (int b = 31; b >= 0; --b) {
            unsigned pb1 = (prefix >> b) | 1u;
            int c1 = 0;
            #pragma unroll
            for (int i = 0; i < 16; ++i) c1 += ((key[i] >> b) == pb1) ? 1 : 0;
            #pragma unroll
            for (int off = 32; off; off >>= 1) c1 += __shfl_xor(c1, off);
            if (c1 >= need) prefix |= (1u << b);
            else need -= c1;
        }
        T = prefix;
        for (int b = 9; b >= 0; --b) {          // v_local < 1024 -> 10 bits
            int c0 = 0;
            #pragma unroll
            for (int i = 0; i < 16; ++i) {
                unsigned vv = (unsigned)(4*lane + 256*(i >> 2) + (i & 3));
                if (key[i] == T && (vv >> (b+1)) == (istar >> (b+1)) && !((vv >> b) & 1u)) c0++;
            }
            #pragma unroll
            for (int off = 32; off; off >>= 1) c0 += __shfl_xor(c0, off);
            if (c0 >= need) { } else { need -= c0; istar |= (1u << b); }
        }
    }

    // gather survivors via shuffle-scan into wave-private LDS
    int mycnt = 0;
    #pragma unroll
    for (int i = 0; i < 16; ++i) {
        unsigned vv = (unsigned)(4*lane + 256*(i >> 2) + (i & 3));
        bool sel = normal ? (key[i] >= tau)
                          : (key[i] > T || (key[i] == T && vv <= istar));
        if (sel) mycnt++;
    }
    int sc = mycnt;
    for (int off = 1; off < 64; off <<= 1) {
        int o = __shfl_up(sc, off);
        if (lane >= off) sc += o;
    }
    int base  = sc - mycnt;
    int total = __shfl(sc, 63);
    int off2  = base;
    #pragma unroll
    for (int i = 0; i < 16; ++i) {
        unsigned vv = (unsigned)(4*lane + 256*(i >> 2) + (i & 3));
        bool sel = normal ? (key[i] >= tau)
                          : (key[i] > T || (key[i] == T && vv <= istar));
        if (sel && off2 < CAPW) {
            s_bk[w][off2] = key[i];
            s_bi[w][off2] = (k << 11) + (half << 10) + (int)vv;   // global cand idx
            off2++;
        }
    }

    // in-wave rank of survivors; rank<32 -> wave's sorted top-32
    for (int e = lane; e < total; e += 64) {
        unsigned mf = s_bk[w][e]; int mi = s_bi[w][e];
        int rank = 0;
        for (int j2 = 0; j2 < total; ++j2) {
            unsigned fq = s_bk[w][j2];
            rank += (fq > mf || (fq == mf && s_bi[w][j2] < mi)) ? 1 : 0;
        }
        if (rank < WID) { s_mk[w*WID + rank] = mf; s_mi[w*WID + rank] = mi; }
    }
    __syncthreads();

    // block merge: exact rank of 128 wave-winners -> block top-32 (covers 2 k-rows)
    if (tid < 4*WID) {
        unsigned mf = s_mk[tid]; int mi = s_mi[tid];
        int rank = 0;
        for (int j2 = 0; j2 < 4*WID; ++j2) {
            unsigned fq = s_mk[j2];
            rank += (fq > mf || (fq == mf && s_mi[j2] < mi)) ? 1 : 0;
        }
        if (rank < WID) { wsF[blk*WID + rank] = mf; wsI[blk*WID + rank] = mi; }
    }
}

// ---------------- kernel B: merge (tau-filtered) + epilogue + prefix + y_next ----------------
__global__ __launch_bounds__(256) void merge_kernel(
    const float* __restrict__ ext,
    const float* __restrict__ nonext,
    const float* __restrict__ blank,
    const float* __restrict__ nbp_g,
    const float* __restrict__ bp_g,
    const int*   __restrict__ yprev,
    const int*   __restrict__ ylast,
    const int*   __restrict__ ylens,
    const int*   __restrict__ pip,
    const unsigned* __restrict__ wsF, const int* __restrict__ wsI,
    float* __restrict__ out)
{
    const int n   = blockIdx.x;
    const int tid = threadIdx.x;

    __shared__ int      s_last[KPP];
    __shared__ float    s_nbp[KPP], s_bp[KPP], s_bne[KPP], s_nbne[KPP];
    __shared__ int      s_tm[KPP][KPP];
    __shared__ unsigned s_exact[KPP];
    __shared__ unsigned s_cf[NLIST];
    __shared__ int      s_ci[NLIST];
    __shared__ unsigned s_ff[NLIST];
    __shared__ int      s_fi[NLIST];
    __shared__ unsigned long long s_tau;
    __shared__ int      s_cnt;
    __shared__ int      s_selidx[WID];
    __shared__ float    s_selval[WID];
    __shared__ int      s_r_src[WID], s_r_lens[WID], s_r_ext[WID], s_r_noext[WID];

    if (tid == 0) s_cnt = 0;
    if (tid < KPP) {
        int k = tid;
        s_exact[k] = 0u;
        int last = ylast[n*KPP + k]; last = min(max(last, 0), VV-1);
        float a = nbp_g[n*KPP + k], b = bp_g[n*KPP + k];
        s_last[k] = last; s_nbp[k] = a; s_bp[k] = b;
        s_bne[k]  = (a + b) * blank[n];
        s_nbne[k] = a * nonext[(size_t)n*VV + last];
    }
    __syncthreads();
    for (int i = tid; i < KPP*KPP; i += 256) {   // (k,j) pairs: to_match + exact bits
        int k = i >> 5, j = i & 31;
        int tlen = ylens[n*KPP + k];
        int tcl  = min(max(tlen, 0), SS-1);
        int tm   = yprev[((size_t)tcl*NB + n)*KPP + j];
        tm = min(max(tm, 0), VV-1);
        s_tm[k][j] = tm;
        bool ex = (tlen + 1 == ylens[n*KPP + j]) && (pip[((size_t)n*KPP + k)*KPP + j] != 0);
        if (ex) atomicOr(&s_exact[k], 1u << j);
    }
    __syncthreads();
    if (tid < KPP) {    // absorb (serial k-order: bit-exact vs reference)
        int j = tid;
        float acc = s_nbne[j];
        for (int k = 0; k < KPP; ++k) {
            if ((s_exact[k] >> j) & 1u) {
                int v = s_tm[k][j];
                float base = (v == s_last[k]) ? 0.0f : s_nbp[k];
                acc += (base + s_bp[k]) * ext[((size_t)n*KPP + k)*VV + v];
            }
        }
        s_nbne[j] = acc;
    }
    __syncthreads();

    // merge list: 512 block winners + 32 nonext
    for (int i = tid; i < NLIST; i += 256) {
        if (i < KBLK*WID) {
            s_cf[i] = wsF[n*KBLK*WID + i];
            s_ci[i] = wsI[n*KBLK*WID + i];
        } else {
            int j = i - KBLK*WID;
            s_cf[i] = fkey(s_nbne[j] + s_bne[j]);
            s_ci[i] = NEXT_BASE + j;
        }
    }
    __syncthreads();

    // tau = max over blocks of their 32nd packed key (lower bound on global 32nd)
    if (tid < 64) {
        unsigned long long p = 0ull;
        if (tid < KBLK) {
            int i = tid*WID + (WID-1);
            p = ((unsigned long long)s_cf[i] << 32) | (unsigned)(~s_ci[i]);
        }
        #pragma unroll
        for (int off = 32; off; off >>= 1) {
            unsigned long long o = shflx64(p, off);
            if (o > p) p = o;
        }
        if (tid == 0) s_tau = p;
    }
    __syncthreads();
    const unsigned long long tau = s_tau;

    for (int i = tid; i < NLIST; i += 256) {
        unsigned long long p = ((unsigned long long)s_cf[i] << 32) | (unsigned)(~s_ci[i]);
        if (p >= tau) {
            int slot = atomicAdd(&s_cnt, 1);
            s_ff[slot] = s_cf[i]; s_fi[slot] = s_ci[i];
        }
    }
    __syncthreads();
    const int cc = s_cnt;

    for (int e = tid; e < cc; e += 256) {
        unsigned mf = s_ff[e]; int mi = s_fi[e];
        int rank = 0;
        for (int j = 0; j < cc; ++j) {
            unsigned f = s_ff[j];
            rank += (f > mf || (f == mf && s_fi[j] < mi)) ? 1 : 0;
        }
        if (rank < WID) { s_selidx[rank] = mi; s_selval[rank] = funkey(mf); }
    }
    __syncthreads();

    // epilogue: per-k scalar outputs
    if (tid < WID) {
        int k = tid;
        int ind = s_selidx[k];
        bool noext = ind >= NEXT_BASE;
        int src  = noext ? (ind - NEXT_BASE) : (ind >> 11);
        int extk = ind & (VV-1);
        int plen = ylens[n*KPP + src];
        int lens = plen + (noext ? 0 : 1);
        float nbv = noext ? s_nbne[src] : s_selval[k];
        float bv  = noext ? s_bne[src]  : 0.0f;
        int lastv = noext ? s_last[src] : extk;
        size_t o = (size_t)n*WID + k;
        out[O_LAST  + o] = (float)lastv;
        out[O_LENS  + o] = (float)lens;
        out[O_NB    + o] = nbv;
        out[O_B     + o] = bv;
        out[O_SRC   + o] = (float)src;
        out[O_NOEXT + o] = noext ? 1.0f : 0.0f;
        s_r_src[k] = src; s_r_lens[k] = lens; s_r_ext[k] = extk;
        s_r_noext[k] = noext ? 1 : 0;
    }
    __syncthreads();

    // fused next_is_prefix (all 1024 (k,j) pairs with 256 threads)
    for (int i = tid; i < WID*WID; i += 256) {
        int k = i >> 5, j = i & 31;
        int src_j = s_r_src[j];
        int no_k  = s_r_noext[k], no_j = s_r_noext[j];
        int lens_k = s_r_lens[k], lens_j = s_r_lens[j];
        int plen_j = lens_j - (no_j ? 0 : 1);
        bool prefix = pip[((size_t)n*KPP + s_r_src[k])*KPP + src_j] != 0;
        bool leq    = lens_k <= lens_j;
        int  tstar  = max(lens_k - 1, 0);
        int  tmj;
        if (tstar == plen_j)   tmj = s_r_ext[j];
        else if (tstar < SS)   tmj = yprev[((size_t)tstar*NB + n)*KPP + src_j];
        else                   tmj = 0;
        bool res = prefix && leq && (no_k || (tmj == s_r_ext[k]));
        out[O_PREF + (size_t)n*WID*WID + i] = res ? 1.0f : 0.0f;
    }

    // fused y_next: out[t][n][k]
    for (int id = tid; id < (SS+1)*WID; id += 256) {
        int t = id >> 5, kq = id & 31;
        int src  = s_r_src[kq];
        int plen = s_r_lens[kq] - (s_r_noext[kq] ? 0 : 1);
        float val;
        if (t == plen)   val = (float)s_r_ext[kq];
        else if (t < SS) val = (float)yprev[((size_t)t*NB + n)*KPP + src];
        else             val = 0.0f;
        out[(size_t)t*NK + (size_t)n*WID + kq] = val;
    }
}

extern "C" void kernel_launch(void* const* d_in, const int* in_sizes, int n_in,
                              void* d_out, int out_size, void* d_ws, size_t ws_size,
                              hipStream_t stream) {
    const float* ext    = (const float*)d_in[0];
    const float* nonext = (const float*)d_in[1];
    const float* blank  = (const float*)d_in[2];
    const float* nbp    = (const float*)d_in[3];
    const float* bp     = (const float*)d_in[4];
    const int*   yprev  = (const int*)d_in[5];
    const int*   ylast  = (const int*)d_in[6];
    const int*   ylens  = (const int*)d_in[7];
    const int*   pip    = (const int*)d_in[8];
    float* out = (float*)d_out;

    unsigned* wsF = (unsigned*)d_ws;                       // NB*KBLK*WID u32
    int*      wsI = (int*)d_ws + NB*KBLK*WID;

    slice_topk_kernel<<<NB*KBLK, 256, 0, stream>>>(ext, nbp, bp, yprev, ylast,
                                                   ylens, pip, wsF, wsI);
    merge_kernel<<<NB, 256, 0, stream>>>(ext, nonext, blank, nbp, bp,
                                         yprev, ylast, ylens, pip, wsF, wsI, out);
}